// Round 1
// baseline (160.610 us; speedup 1.0000x reference)
//
#include <hip/hip_runtime.h>
#include <math.h>

#define BATCH 8192
#define STATE_DIM 4096

__global__ __launch_bounds__(256) void _MambaState_73632919322669_kernel(
    const float* __restrict__ prev,
    const float* __restrict__ b_t,
    const float* __restrict__ v_t,
    const float* __restrict__ c_t,
    const float* __restrict__ a_logit,
    const float* __restrict__ delta_log,
    float* __restrict__ out_state,
    float* __restrict__ out_y)
{
    constexpr int VPR = STATE_DIM / 4;  // 1024 float4 vectors per row

    const int tid = blockIdx.x * blockDim.x + threadIdx.x;
    const int vc = tid & (VPR - 1);          // vector-column, fixed per thread
    const int row0 = tid >> 10;              // tid / VPR
    const int rowStride = (gridDim.x * blockDim.x) >> 10;

    // Broadcast params: compute once per thread (accurate, not fast-math)
    const float4 al = *reinterpret_cast<const float4*>(a_logit + vc * 4);
    const float4 dl = *reinterpret_cast<const float4*>(delta_log + vc * 4);

    float4 a, dt;
    a.x = 1.0f / (1.0f + expf(-al.x));
    a.y = 1.0f / (1.0f + expf(-al.y));
    a.z = 1.0f / (1.0f + expf(-al.z));
    a.w = 1.0f / (1.0f + expf(-al.w));
    dt.x = log1pf(expf(dl.x));
    dt.y = log1pf(expf(dl.y));
    dt.z = log1pf(expf(dl.z));
    dt.w = log1pf(expf(dl.w));

    const float4* __restrict__ prev4 = reinterpret_cast<const float4*>(prev);
    const float4* __restrict__ b4    = reinterpret_cast<const float4*>(b_t);
    const float4* __restrict__ v4    = reinterpret_cast<const float4*>(v_t);
    const float4* __restrict__ c4    = reinterpret_cast<const float4*>(c_t);
    float4* __restrict__ os4 = reinterpret_cast<float4*>(out_state);
    float4* __restrict__ oy4 = reinterpret_cast<float4*>(out_y);

    for (int row = row0; row < BATCH; row += rowStride) {
        const long long idx = (long long)row * VPR + vc;
        const float4 p  = prev4[idx];
        const float4 bb = b4[idx];
        const float4 vv = v4[idx];
        const float4 cc = c4[idx];

        float4 ns, yy;
        ns.x = a.x * p.x + dt.x * (bb.x * vv.x);
        ns.y = a.y * p.y + dt.y * (bb.y * vv.y);
        ns.z = a.z * p.z + dt.z * (bb.z * vv.z);
        ns.w = a.w * p.w + dt.w * (bb.w * vv.w);
        yy.x = cc.x * ns.x;
        yy.y = cc.y * ns.y;
        yy.z = cc.z * ns.z;
        yy.w = cc.w * ns.w;

        os4[idx] = ns;
        oy4[idx] = yy;
    }
}

extern "C" void kernel_launch(void* const* d_in, const int* in_sizes, int n_in,
                              void* d_out, int out_size, void* d_ws, size_t ws_size,
                              hipStream_t stream) {
    const float* prev      = (const float*)d_in[0];
    const float* b_t       = (const float*)d_in[1];
    const float* v_t       = (const float*)d_in[2];
    const float* c_t       = (const float*)d_in[3];
    const float* a_logit   = (const float*)d_in[4];
    const float* delta_log = (const float*)d_in[5];

    float* out_state = (float*)d_out;
    float* out_y     = out_state + (size_t)BATCH * STATE_DIM;

    dim3 grid(2048), block(256);
    _MambaState_73632919322669_kernel<<<grid, block, 0, stream>>>(
        prev, b_t, v_t, c_t, a_logit, delta_log, out_state, out_y);
}

// Round 2
// 159.210 us; speedup vs baseline: 1.0088x; 1.0088x over previous
//
#include <hip/hip_runtime.h>
#include <math.h>

#define BATCH 8192
#define STATE_DIM 4096

__global__ __launch_bounds__(256) void _MambaState_73632919322669_kernel(
    const float* __restrict__ prev,
    const float* __restrict__ b_t,
    const float* __restrict__ v_t,
    const float* __restrict__ c_t,
    const float* __restrict__ a_logit,
    const float* __restrict__ delta_log,
    float* __restrict__ out_state,
    float* __restrict__ out_y)
{
    constexpr int VPR = STATE_DIM / 4;   // 1024 float4 vectors per row
    constexpr int ROWSTRIDE = 512;       // (2048 blocks * 256 thr) >> 10
    constexpr int UNROLL = 4;

    const int tid = blockIdx.x * blockDim.x + threadIdx.x;
    const int vc = tid & (VPR - 1);      // vector-column, fixed per thread
    const int row0 = tid >> 10;          // 0..511

    // Broadcast params: compute once per thread (accurate, not fast-math)
    const float4 al = *reinterpret_cast<const float4*>(a_logit + vc * 4);
    const float4 dl = *reinterpret_cast<const float4*>(delta_log + vc * 4);

    float4 a, dt;
    a.x = 1.0f / (1.0f + expf(-al.x));
    a.y = 1.0f / (1.0f + expf(-al.y));
    a.z = 1.0f / (1.0f + expf(-al.z));
    a.w = 1.0f / (1.0f + expf(-al.w));
    dt.x = log1pf(expf(dl.x));
    dt.y = log1pf(expf(dl.y));
    dt.z = log1pf(expf(dl.z));
    dt.w = log1pf(expf(dl.w));

    const float4* __restrict__ prev4 = reinterpret_cast<const float4*>(prev);
    const float4* __restrict__ b4    = reinterpret_cast<const float4*>(b_t);
    const float4* __restrict__ v4    = reinterpret_cast<const float4*>(v_t);
    const float4* __restrict__ c4    = reinterpret_cast<const float4*>(c_t);
    float4* __restrict__ os4 = reinterpret_cast<float4*>(out_state);
    float4* __restrict__ oy4 = reinterpret_cast<float4*>(out_y);

    // 16 rows per thread, processed 4 at a time with all loads issued first.
    for (int it = 0; it < BATCH / ROWSTRIDE; it += UNROLL) {
        int idx[UNROLL];
        float4 p[UNROLL], bb[UNROLL], vv[UNROLL], cc[UNROLL];

        #pragma unroll
        for (int u = 0; u < UNROLL; ++u) {
            const int row = row0 + (it + u) * ROWSTRIDE;
            idx[u] = row * VPR + vc;     // max 8.4M, fits int32
        }
        // issue all 16 loads before any use -> 16 outstanding per wave
        #pragma unroll
        for (int u = 0; u < UNROLL; ++u) p[u]  = prev4[idx[u]];
        #pragma unroll
        for (int u = 0; u < UNROLL; ++u) bb[u] = b4[idx[u]];
        #pragma unroll
        for (int u = 0; u < UNROLL; ++u) vv[u] = v4[idx[u]];
        #pragma unroll
        for (int u = 0; u < UNROLL; ++u) cc[u] = c4[idx[u]];

        #pragma unroll
        for (int u = 0; u < UNROLL; ++u) {
            float4 ns, yy;
            ns.x = a.x * p[u].x + dt.x * (bb[u].x * vv[u].x);
            ns.y = a.y * p[u].y + dt.y * (bb[u].y * vv[u].y);
            ns.z = a.z * p[u].z + dt.z * (bb[u].z * vv[u].z);
            ns.w = a.w * p[u].w + dt.w * (bb[u].w * vv[u].w);
            yy.x = cc[u].x * ns.x;
            yy.y = cc[u].y * ns.y;
            yy.z = cc[u].z * ns.z;
            yy.w = cc[u].w * ns.w;
            os4[idx[u]] = ns;
            oy4[idx[u]] = yy;
        }
    }
}

extern "C" void kernel_launch(void* const* d_in, const int* in_sizes, int n_in,
                              void* d_out, int out_size, void* d_ws, size_t ws_size,
                              hipStream_t stream) {
    const float* prev      = (const float*)d_in[0];
    const float* b_t       = (const float*)d_in[1];
    const float* v_t       = (const float*)d_in[2];
    const float* c_t       = (const float*)d_in[3];
    const float* a_logit   = (const float*)d_in[4];
    const float* delta_log = (const float*)d_in[5];

    float* out_state = (float*)d_out;
    float* out_y     = out_state + (size_t)BATCH * STATE_DIM;

    dim3 grid(2048), block(256);
    _MambaState_73632919322669_kernel<<<grid, block, 0, stream>>>(
        prev, b_t, v_t, c_t, a_logit, delta_log, out_state, out_y);
}